// Round 8
// baseline (523.434 us; speedup 1.0000x reference)
//
#include <hip/hip_runtime.h>
#include <math.h>

constexpr int NROWS = 32768;   // B
constexpr int DIMC  = 256;     // D
constexpr int KC    = 4096;    // K

typedef __attribute__((ext_vector_type(8))) short short8;
typedef __attribute__((ext_vector_type(4))) float f32x4;

struct alignas(16) Part { float d1; int i1; float d2; int i2; };

// ambiguity window: ~15 sigma of the h-only bf16 approx error (validated r7)
#define WIN 3.0e-4f

__device__ __forceinline__ unsigned short f2bf(float x) {
  unsigned u = __float_as_uint(x);
  return (unsigned short)((u + 0x7fffu + ((u >> 16) & 1u)) >> 16);
}

// ---------------------------------------------------------------------------
// Fused pre-pass: one wave per row. Rows [0,NROWS) -> Zb (row-major bf16) +
// anorm (fp32 of f64 sum of squares); rows [NROWS, NROWS+KC) -> Wb.
// ---------------------------------------------------------------------------
__global__ __launch_bounds__(256)
void vq_prep(const float* __restrict__ Z, const float* __restrict__ W,
             unsigned short* __restrict__ Zb, unsigned short* __restrict__ Wb,
             float* __restrict__ anorm) {
  const int lane = threadIdx.x & 63, wv = threadIdx.x >> 6;
  const int row = blockIdx.x * 4 + wv;
  if (row < NROWS) {
    const float4 z4 = *(const float4*)(Z + (size_t)row * DIMC + lane * 4);
    ushort4 b;
    b.x = f2bf(z4.x); b.y = f2bf(z4.y); b.z = f2bf(z4.z); b.w = f2bf(z4.w);
    *(ushort4*)(Zb + (size_t)row * DIMC + lane * 4) = b;
    double s = (double)z4.x * z4.x + (double)z4.y * z4.y +
               (double)z4.z * z4.z + (double)z4.w * z4.w;
#pragma unroll
    for (int off = 32; off > 0; off >>= 1) s += __shfl_down(s, off);
    if (lane == 0) anorm[row] = (float)s;
  } else {
    const int wr = row - NROWS;
    const float4 w4 = *(const float4*)(W + (size_t)wr * DIMC + lane * 4);
    ushort4 b;
    b.x = f2bf(w4.x); b.y = f2bf(w4.y); b.z = f2bf(w4.z); b.w = f2bf(w4.w);
    *(ushort4*)(Wb + (size_t)wr * DIMC + lane * 4) = b;
  }
}

// ---------------------------------------------------------------------------
// Main: LDS-free bf16 MFMA GEMM. A/B fragments are 16 contiguous bytes of the
// row-major bf16 matrices (lane m = lane&15 -> row/col m, k-octet = lane>>4),
// loaded directly from L1/L2 (W is 2MB, L2-resident; A rows reused 32x).
// No barriers in the K-loop. Epilogue: per-(row, colblock) exact top-2 of
// d = a - 2f*dot (identical math to r7's validated epilogue).
// ---------------------------------------------------------------------------
__global__ __launch_bounds__(256, 4)
void vq_mfma(const unsigned short* __restrict__ Zb, const unsigned short* __restrict__ Wb,
             const float* __restrict__ anorm, Part* __restrict__ partial) {
  __shared__ float pd1[256];
  __shared__ int   pi1[256];
  __shared__ float pd2[256];

  const int t = threadIdx.x, lane = t & 63, w = t >> 6;
  const int rb = blockIdx.x >> 5, cb = blockIdx.x & 31;
  const int q = lane >> 4, ml = lane & 15;
  const int wr = w >> 1, wc = w & 1;

  const unsigned short* Abase = Zb + (size_t)(rb * 128 + wr * 64 + ml) * DIMC + q * 8;
  const unsigned short* Bbase = Wb + (size_t)(cb * 128 + wc * 64 + ml) * DIMC + q * 8;

  f32x4 acc[4][4];
#pragma unroll
  for (int i = 0; i < 4; ++i)
#pragma unroll
    for (int j = 0; j < 4; ++j) acc[i][j] = (f32x4){0.f, 0.f, 0.f, 0.f};

#pragma unroll
  for (int kb = 0; kb < 8; ++kb) {
    short8 Af[4], Bf[4];
#pragma unroll
    for (int i = 0; i < 4; ++i) {
      Af[i] = *(const short8*)(Abase + (size_t)i * 16 * DIMC + kb * 32);
      Bf[i] = *(const short8*)(Bbase + (size_t)i * 16 * DIMC + kb * 32);
    }
#pragma unroll
    for (int i = 0; i < 4; ++i)
#pragma unroll
      for (int j = 0; j < 4; ++j)
        acc[i][j] = __builtin_amdgcn_mfma_f32_16x16x32_bf16(Af[i], Bf[j], acc[i][j], 0, 0, 0);
  }

  const float INF = 3.4e38f;
#pragma unroll
  for (int i = 0; i < 4; ++i) {
#pragma unroll
    for (int r = 0; r < 4; ++r) {
      const int lr = i * 16 + q * 4 + r;
      const float am = anorm[rb * 128 + wr * 64 + lr];
      float d1m = INF, d2m = INF; int i1m = 0x7fffffff;
#pragma unroll
      for (int j = 0; j < 4; ++j) {
        const float d = am - 2.0f * acc[i][j][r];
        const int idx = cb * 128 + wc * 64 + j * 16 + ml;
        if (d < d1m || (d == d1m && idx < i1m)) { d2m = d1m; d1m = d; i1m = idx; }
        else d2m = fminf(d2m, d);
      }
#pragma unroll
      for (int mask = 1; mask < 16; mask <<= 1) {
        const float od1 = __shfl_xor(d1m, mask);
        const int   oi1 = __shfl_xor(i1m, mask);
        const float od2 = __shfl_xor(d2m, mask);
        if (od1 < d1m || (od1 == d1m && oi1 < i1m)) {
          d2m = fminf(d1m, od2); d1m = od1; i1m = oi1;
        } else d2m = fminf(d2m, od1);
      }
      if (ml == 0) { pd1[w * 64 + lr] = d1m; pi1[w * 64 + lr] = i1m; pd2[w * 64 + lr] = d2m; }
    }
  }
  __syncthreads();
  if (t < 128) {
    const int wrh = t >> 6, lr = t & 63;
    const int e0 = (wrh * 2 + 0) * 64 + lr, e1 = (wrh * 2 + 1) * 64 + lr;
    const float d1a = pd1[e0], d2a = pd2[e0]; const int i1a = pi1[e0];
    const float d1b = pd1[e1], d2b = pd2[e1]; const int i1b = pi1[e1];
    Part p;
    if (d1b < d1a || (d1b == d1a && i1b < i1a)) { p.d1 = d1b; p.i1 = i1b; p.d2 = fminf(d1a, d2b); }
    else                                        { p.d1 = d1a; p.i1 = i1a; p.d2 = fminf(d1b, d2a); }
    p.i2 = 0;
    const int row = rb * 128 + wrh * 64 + lr;
    partial[(size_t)row * 32 + cb] = p;
  }
}

// ---------------------------------------------------------------------------
// Exact np-semantics distance (byte-identical chain to rounds 2-7).
// ---------------------------------------------------------------------------
__device__ __forceinline__ float exact_d(const float* __restrict__ Z,
                                         const float* __restrict__ W,
                                         int row, int c, float a) {
  const float* z = Z + (size_t)row * DIMC;
  const float* w = W + (size_t)c * DIMC;
  float dot = 0.f;
  for (int d0 = 0; d0 < DIMC; d0 += 4) {
    const float4 zv = *(const float4*)(z + d0);
    const float4 wv = *(const float4*)(w + d0);
    dot = fmaf(zv.x, wv.x, dot);
    dot = fmaf(zv.y, wv.y, dot);
    dot = fmaf(zv.z, wv.z, dot);
    dot = fmaf(zv.w, wv.w, dot);
  }
  return a - 2.0f * dot;
}

// ---------------------------------------------------------------------------
// Fused tail: one wave per row. Butterfly-merge the 32 colblock partials
// (lexicographic top-1 + global 2nd-best); if gap > WIN take approx argmin,
// else exact-resolve candidates (r7-validated rule). Then gather z_q, write
// indices, accumulate f64 loss + histogram.
// ---------------------------------------------------------------------------
__global__ __launch_bounds__(256)
void vq_tail(const float* __restrict__ Z, const float* __restrict__ W,
             const float* __restrict__ anorm, const Part* __restrict__ partial,
             float* __restrict__ zq_out, float* __restrict__ idx_out,
             double* __restrict__ loss_acc, int* __restrict__ hist) {
  __shared__ double sh[4];
  const int lane = threadIdx.x & 63, wv = threadIdx.x >> 6;
  const int row = blockIdx.x * 4 + wv;
  const float INF = 3.4e38f;

  float d1 = INF, d2 = INF; int i1 = 0x7fffffff;
  if (lane < 32) {
    const Part p = partial[(size_t)row * 32 + lane];
    d1 = p.d1; d2 = p.d2; i1 = p.i1;
  }
  // 5-stage top-2 merge across lanes 0..31 (lanes 32+ hold INF, stay inert)
  float g1 = d1, g2 = d2; int gi = i1;
#pragma unroll
  for (int mask = 1; mask < 32; mask <<= 1) {
    const float og1 = __shfl_xor(g1, mask);
    const int   ogi = __shfl_xor(gi, mask);
    const float og2 = __shfl_xor(g2, mask);
    if (og1 < g1 || (og1 == g1 && ogi < gi)) {
      g2 = fminf(g1, og2); g1 = og1; gi = ogi;
    } else g2 = fminf(g2, og1);
  }
  g1 = __shfl(g1, 0); g2 = __shfl(g2, 0); gi = __shfl(gi, 0);

  int k;
  if (g2 - g1 > WIN) {
    k = gi;
  } else {
    const float a = anorm[row];
    const float thr = g1 + WIN;
    const bool scan   = (lane < 32) && (d2 <= thr);
    const bool single = (lane < 32) && !scan && (d1 <= thr);
    float bd = INF; int bi = 0x7fffffff;
    if (single) {
      const float d = exact_d(Z, W, row, i1, a);
      if (d < bd || (d == bd && i1 < bi)) { bd = d; bi = i1; }
    }
    unsigned long long msk = __ballot(scan);
    while (msk) {
      const int cbk = __ffsll(msk) - 1; msk &= msk - 1;
#pragma unroll
      for (int h = 0; h < 2; ++h) {
        const int c = cbk * 128 + h * 64 + lane;
        const float d = exact_d(Z, W, row, c, a);
        if (d < bd || (d == bd && c < bi)) { bd = d; bi = c; }
      }
    }
#pragma unroll
    for (int mask = 1; mask < 64; mask <<= 1) {
      const float od = __shfl_xor(bd, mask);
      const int   oi = __shfl_xor(bi, mask);
      if (od < bd || (od == bd && oi < bi)) { bd = od; bi = oi; }
    }
    k = bi;
  }

  // gather + outputs (identical to validated vq_select)
  const float4 z4 = *(const float4*)(Z + (size_t)row * DIMC + lane * 4);
  const float4 w4 = *(const float4*)(W + (size_t)k   * DIMC + lane * 4);
  *(float4*)(zq_out + (size_t)row * DIMC + lane * 4) = w4;

  const double dx = (double)w4.x - (double)z4.x;
  const double dy = (double)w4.y - (double)z4.y;
  const double dz = (double)w4.z - (double)z4.z;
  const double dw = (double)w4.w - (double)z4.w;
  double l = dx * dx + dy * dy + dz * dz + dw * dw;
#pragma unroll
  for (int off = 32; off > 0; off >>= 1) l += __shfl_down(l, off);

  if (lane == 0) { sh[wv] = l; idx_out[row] = (float)k; atomicAdd(&hist[k], 1); }
  __syncthreads();
  if (threadIdx.x == 0) unsafeAtomicAdd(loss_acc, sh[0] + sh[1] + sh[2] + sh[3]);
}

__global__ __launch_bounds__(64)
void vq_final(const double* __restrict__ loss_acc, const int* __restrict__ hist,
              float* __restrict__ scal) {
  const int lane = threadIdx.x;
  double H = 0.0;
  for (int k = lane; k < KC; k += 64) {
    const double p = (double)hist[k] / (double)NROWS;
    H -= p * log(p + 1e-10);
  }
#pragma unroll
  for (int off = 32; off > 0; off >>= 1) H += __shfl_down(H, off);
  if (lane == 0) {
    scal[0] = (float)(loss_acc[0] * 1.25 / ((double)NROWS * (double)DIMC));
    scal[1] = (float)exp(H);
  }
}

// ---------------------------------------------------------------------------
extern "C" void kernel_launch(void* const* d_in, const int* in_sizes, int n_in,
                              void* d_out, int out_size, void* d_ws, size_t ws_size,
                              hipStream_t stream) {
  const float* Z = (const float*)d_in[0];
  const float* W = (const float*)d_in[1];
  float* out = (float*)d_out;
  float* zq_out  = out;
  float* idx_out = out + (size_t)NROWS * DIMC;
  float* scal    = idx_out + NROWS;

  char* ws = (char*)d_ws;
  double* loss_acc   = (double*)ws;                       // 8 B @0
  int*    hist       = (int*)(ws + 1024);                 // 16 KB
  float*  anorm      = (float*)(ws + 163840);             // 128 KB
  Part*   partial    = (Part*)(ws + 1048576);             // 16 MB @ 1 MB
  unsigned short* Zb = (unsigned short*)(ws + 20971520);  // 16 MB @ 20 MB
  unsigned short* Wb = (unsigned short*)(ws + 37748736);  // 2 MB  @ 36 MB

  hipMemsetAsync(ws, 0, 17408, stream);                   // loss + hist
  vq_prep<<<(NROWS + KC) / 4, 256, 0, stream>>>(Z, W, Zb, Wb, anorm);
  vq_mfma<<<8192, 256, 0, stream>>>(Zb, Wb, anorm, partial);
  vq_tail<<<NROWS / 4, 256, 0, stream>>>(Z, W, anorm, partial, zq_out, idx_out, loss_acc, hist);
  vq_final<<<1, 64, 0, stream>>>(loss_acc, hist, scal);
}

// Round 9
// 331.268 us; speedup vs baseline: 1.5801x; 1.5801x over previous
//
#include <hip/hip_runtime.h>
#include <math.h>

constexpr int NROWS = 32768;   // B
constexpr int DIMC  = 256;     // D
constexpr int KC    = 4096;    // K

typedef __attribute__((ext_vector_type(8))) short short8;
typedef __attribute__((ext_vector_type(4))) float f32x4;

#define AS1 __attribute__((address_space(1)))
#define AS3 __attribute__((address_space(3)))

struct alignas(16) Part { float d1; int i1; float d2; int i2; };

// ambiguity window: validated r7 (~15 sigma of h-only bf16 approx error)
#define WIN 3.0e-4f

__device__ __forceinline__ unsigned short f2bf(float x) {
  unsigned u = __float_as_uint(x);
  return (unsigned short)((u + 0x7fffu + ((u >> 16) & 1u)) >> 16);
}

// ---------------------------------------------------------------------------
// Fused split: h-plane bf16 in the GEMM's tiled, swizzled HBM layout
// [blk128][kblk(8)][granule g=r*4+slot], slot holds octet s8=slot^((r>>1)&3).
// bid < 2048 -> Z tiles; bid 2048..2303 -> W tiles. (layout validated r3-r7)
// ---------------------------------------------------------------------------
__global__ __launch_bounds__(256)
void vq_split(const float* __restrict__ Z, const float* __restrict__ W,
              unsigned short* __restrict__ Zh, unsigned short* __restrict__ Wh) {
  const bool isW = blockIdx.x >= 2048;
  const int bid  = isW ? (blockIdx.x - 2048) : blockIdx.x;
  const float* X = isW ? W : Z;
  unsigned short* out = isW ? Wh : Zh;
  const int blk = bid >> 3;
  const int kb  = bid & 7;
  const int t = threadIdx.x;
#pragma unroll
  for (int gi = 0; gi < 2; ++gi) {
    const int g = t + gi * 256;
    const int r = g >> 2, slot = g & 3;
    const int s8 = slot ^ ((r >> 1) & 3);
    const float* src = X + (size_t)(blk * 128 + r) * DIMC + kb * 32 + s8 * 8;
    short8 vh;
#pragma unroll
    for (int j = 0; j < 8; ++j) vh[j] = (short)f2bf(src[j]);
    *(short8*)(out + ((size_t)blk * 8 + kb) * 4096 + g * 8) = vh;
  }
}

// ---------------------------------------------------------------------------
__global__ __launch_bounds__(256)
void vq_rownorm(const float* __restrict__ Z, float* __restrict__ anorm) {
  const int lane = threadIdx.x & 63;
  const int wv   = threadIdx.x >> 6;
  const int row  = blockIdx.x * 4 + wv;
  const float4 z4 = *(const float4*)(Z + (size_t)row * DIMC + lane * 4);
  double s = (double)z4.x * z4.x + (double)z4.y * z4.y +
             (double)z4.z * z4.z + (double)z4.w * z4.w;
#pragma unroll
  for (int off = 32; off > 0; off >>= 1) s += __shfl_down(s, off);
  if (lane == 0) anorm[row] = (float)s;
}

// ---------------------------------------------------------------------------
// Main: h-only bf16 MFMA GEMM, r7's validated LDS staging (global_load_lds,
// conflict-free swizzle). NEW epilogue: u32-key top-2 (key = quantized -acc
// || local col; anorm cancels out of argmin) reduced across the 16-lane row
// group with DPP row_ror stages (no ds_bpermute, no float compare chains).
// ---------------------------------------------------------------------------
#define DPP_STAGE(CTRL)                                                        \
  {                                                                            \
    unsigned n1 = (unsigned)__builtin_amdgcn_update_dpp((int)k1, (int)k1,      \
                                                        CTRL, 0xF, 0xF, false);\
    unsigned n2 = (unsigned)__builtin_amdgcn_update_dpp((int)k2, (int)k2,      \
                                                        CTRL, 0xF, 0xF, false);\
    const unsigned tmax = max(k1, n1);                                         \
    k1 = min(k1, n1);                                                          \
    k2 = min(min(k2, n2), tmax);                                               \
  }

__global__ __launch_bounds__(256, 4)
void vq_mfma(const unsigned short* __restrict__ Zh, const unsigned short* __restrict__ Wh,
             const float* __restrict__ anorm, Part* __restrict__ partial) {
  __shared__ char lds[16384];          // A: [0,8K), B: [8K,16K)
  const int t = threadIdx.x, lane = t & 63, w = t >> 6;
  const int rb = blockIdx.x >> 5, cb = blockIdx.x & 31;
  const int q = lane >> 4, ml = lane & 15;
  const int wr = w >> 1, wc = w & 1;

  const unsigned short* src0 = (w < 2) ? Zh + (size_t)rb * 32768
                                       : Wh + (size_t)cb * 32768;
  const int half = w & 1;
  char* ldsdst = lds + (w >> 1) * 8192 + half * 4096;

  int aoff[4], boff[4];
#pragma unroll
  for (int i = 0; i < 4; ++i) {
    const int r = wr * 64 + i * 16 + ml;
    aoff[i] = (r * 4 + (q ^ ((r >> 1) & 3))) * 16;
    const int c = wc * 64 + i * 16 + ml;
    boff[i] = (c * 4 + (q ^ ((c >> 1) & 3))) * 16;
  }

  f32x4 acc[4][4];
#pragma unroll
  for (int i = 0; i < 4; ++i)
#pragma unroll
    for (int j = 0; j < 4; ++j) acc[i][j] = (f32x4){0.f, 0.f, 0.f, 0.f};

  for (int kb = 0; kb < 8; ++kb) {
    __syncthreads();
    const unsigned short* s = src0 + kb * 4096 + half * 2048 + lane * 8;
#pragma unroll
    for (int i = 0; i < 4; ++i)
      __builtin_amdgcn_global_load_lds((const AS1 void*)(s + i * 512),
                                       (AS3 void*)(ldsdst + i * 1024), 16, 0, 0);
    __syncthreads();
    short8 Ah[4], Bh[4];
#pragma unroll
    for (int i = 0; i < 4; ++i) {
      Ah[i] = *(const short8*)(lds +        aoff[i]);
      Bh[i] = *(const short8*)(lds + 8192 + boff[i]);
    }
#pragma unroll
    for (int i = 0; i < 4; ++i)
#pragma unroll
      for (int j = 0; j < 4; ++j)
        acc[i][j] = __builtin_amdgcn_mfma_f32_16x16x32_bf16(Ah[i], Bh[j], acc[i][j], 0, 0, 0);
  }

  // ------ key-based epilogue ------
  __syncthreads();                      // LDS reuse for per-wave results
  uint2* pk = (uint2*)lds;              // [4 waves][64 rows]
  const float SC = 33554432.0f;         // 2^25; |acc| < 0.06 -> 0.125-acc in (0,0.25)

#pragma unroll
  for (int i = 0; i < 4; ++i) {
#pragma unroll
    for (int r = 0; r < 4; ++r) {
      unsigned k[4];
#pragma unroll
      for (int j = 0; j < 4; ++j) {
        const unsigned qv = (unsigned)((0.125f - acc[i][j][r]) * SC);
        k[j] = (qv << 7) | (unsigned)(wc * 64 + j * 16 + ml);
      }
      const unsigned m01 = min(k[0], k[1]), x01 = max(k[0], k[1]);
      const unsigned m23 = min(k[2], k[3]), x23 = max(k[2], k[3]);
      unsigned k1 = min(m01, m23);
      unsigned k2 = min(min(x01, x23), max(m01, m23));
      DPP_STAGE(0x121)   // row_ror:1
      DPP_STAGE(0x122)   // row_ror:2
      DPP_STAGE(0x124)   // row_ror:4
      DPP_STAGE(0x128)   // row_ror:8
      if (ml == 0) pk[w * 64 + (i * 16 + q * 4 + r)] = make_uint2(k1, k2);
    }
  }
  __syncthreads();
  if (t < 128) {
    const int wrh = t >> 6, lr = t & 63;
    const uint2 A2 = pk[(wrh * 2 + 0) * 64 + lr];
    const uint2 B2 = pk[(wrh * 2 + 1) * 64 + lr];
    const unsigned k1 = min(A2.x, B2.x);
    const unsigned k2 = min(min(A2.y, B2.y), max(A2.x, B2.x));
    const int row = rb * 128 + wrh * 64 + lr;
    const float am = anorm[row];
    const float inv = 2.9802322387695312e-08f;   // 2^-25
    const float dot1 = 0.125f - (float)(k1 >> 7) * inv;
    const float dot2 = 0.125f - (float)(k2 >> 7) * inv;
    Part p;
    p.d1 = am - 2.0f * dot1;
    p.i1 = cb * 128 + (int)(k1 & 127u);
    p.d2 = am - 2.0f * dot2;
    p.i2 = 0;
    partial[(size_t)row * 32 + cb] = p;
  }
}

// ---------------------------------------------------------------------------
// Exact np-semantics distance (byte-identical chain to rounds 2-8).
// ---------------------------------------------------------------------------
__device__ __forceinline__ float exact_d(const float* __restrict__ Z,
                                         const float* __restrict__ W,
                                         int row, int c, float a) {
  const float* z = Z + (size_t)row * DIMC;
  const float* w = W + (size_t)c * DIMC;
  float dot = 0.f;
  for (int d0 = 0; d0 < DIMC; d0 += 4) {
    const float4 zv = *(const float4*)(z + d0);
    const float4 wv = *(const float4*)(w + d0);
    dot = fmaf(zv.x, wv.x, dot);
    dot = fmaf(zv.y, wv.y, dot);
    dot = fmaf(zv.z, wv.z, dot);
    dot = fmaf(zv.w, wv.w, dot);
  }
  return a - 2.0f * dot;
}

// ---------------------------------------------------------------------------
// Fused tail (validated r8): merge partials, WIN-gated exact resolve, gather
// z_q, indices, f64 loss + histogram.
// ---------------------------------------------------------------------------
__global__ __launch_bounds__(256)
void vq_tail(const float* __restrict__ Z, const float* __restrict__ W,
             const float* __restrict__ anorm, const Part* __restrict__ partial,
             float* __restrict__ zq_out, float* __restrict__ idx_out,
             double* __restrict__ loss_acc, int* __restrict__ hist) {
  __shared__ double sh[4];
  const int lane = threadIdx.x & 63, wv = threadIdx.x >> 6;
  const int row = blockIdx.x * 4 + wv;
  const float INF = 3.4e38f;

  float d1 = INF, d2 = INF; int i1 = 0x7fffffff;
  if (lane < 32) {
    const Part p = partial[(size_t)row * 32 + lane];
    d1 = p.d1; d2 = p.d2; i1 = p.i1;
  }
  float g1 = d1, g2 = d2; int gi = i1;
#pragma unroll
  for (int mask = 1; mask < 32; mask <<= 1) {
    const float og1 = __shfl_xor(g1, mask);
    const int   ogi = __shfl_xor(gi, mask);
    const float og2 = __shfl_xor(g2, mask);
    if (og1 < g1 || (og1 == g1 && ogi < gi)) {
      g2 = fminf(g1, og2); g1 = og1; gi = ogi;
    } else g2 = fminf(g2, og1);
  }
  g1 = __shfl(g1, 0); g2 = __shfl(g2, 0); gi = __shfl(gi, 0);

  int k;
  if (g2 - g1 > WIN) {
    k = gi;
  } else {
    const float a = anorm[row];
    const float thr = g1 + WIN;
    const bool scan   = (lane < 32) && (d2 <= thr);
    const bool single = (lane < 32) && !scan && (d1 <= thr);
    float bd = INF; int bi = 0x7fffffff;
    if (single) {
      const float d = exact_d(Z, W, row, i1, a);
      if (d < bd || (d == bd && i1 < bi)) { bd = d; bi = i1; }
    }
    unsigned long long msk = __ballot(scan);
    while (msk) {
      const int cbk = __ffsll(msk) - 1; msk &= msk - 1;
#pragma unroll
      for (int h = 0; h < 2; ++h) {
        const int c = cbk * 128 + h * 64 + lane;
        const float d = exact_d(Z, W, row, c, a);
        if (d < bd || (d == bd && c < bi)) { bd = d; bi = c; }
      }
    }
#pragma unroll
    for (int mask = 1; mask < 64; mask <<= 1) {
      const float od = __shfl_xor(bd, mask);
      const int   oi = __shfl_xor(bi, mask);
      if (od < bd || (od == bd && oi < bi)) { bd = od; bi = oi; }
    }
    k = bi;
  }

  const float4 z4 = *(const float4*)(Z + (size_t)row * DIMC + lane * 4);
  const float4 w4 = *(const float4*)(W + (size_t)k   * DIMC + lane * 4);
  *(float4*)(zq_out + (size_t)row * DIMC + lane * 4) = w4;

  const double dx = (double)w4.x - (double)z4.x;
  const double dy = (double)w4.y - (double)z4.y;
  const double dz = (double)w4.z - (double)z4.z;
  const double dw = (double)w4.w - (double)z4.w;
  double l = dx * dx + dy * dy + dz * dz + dw * dw;
#pragma unroll
  for (int off = 32; off > 0; off >>= 1) l += __shfl_down(l, off);

  if (lane == 0) { sh[wv] = l; idx_out[row] = (float)k; atomicAdd(&hist[k], 1); }
  __syncthreads();
  if (threadIdx.x == 0) unsafeAtomicAdd(loss_acc, sh[0] + sh[1] + sh[2] + sh[3]);
}

__global__ __launch_bounds__(64)
void vq_final(const double* __restrict__ loss_acc, const int* __restrict__ hist,
              float* __restrict__ scal) {
  const int lane = threadIdx.x;
  double H = 0.0;
  for (int k = lane; k < KC; k += 64) {
    const double p = (double)hist[k] / (double)NROWS;
    H -= p * log(p + 1e-10);
  }
#pragma unroll
  for (int off = 32; off > 0; off >>= 1) H += __shfl_down(H, off);
  if (lane == 0) {
    scal[0] = (float)(loss_acc[0] * 1.25 / ((double)NROWS * (double)DIMC));
    scal[1] = (float)exp(H);
  }
}

// ---------------------------------------------------------------------------
extern "C" void kernel_launch(void* const* d_in, const int* in_sizes, int n_in,
                              void* d_out, int out_size, void* d_ws, size_t ws_size,
                              hipStream_t stream) {
  const float* Z = (const float*)d_in[0];
  const float* W = (const float*)d_in[1];
  float* out = (float*)d_out;
  float* zq_out  = out;
  float* idx_out = out + (size_t)NROWS * DIMC;
  float* scal    = idx_out + NROWS;

  char* ws = (char*)d_ws;
  double* loss_acc   = (double*)ws;                       // 8 B @0
  int*    hist       = (int*)(ws + 1024);                 // 16 KB
  float*  anorm      = (float*)(ws + 163840);             // 128 KB
  Part*   partial    = (Part*)(ws + 1048576);             // 16 MB @ 1 MB
  unsigned short* Zh = (unsigned short*)(ws + 20971520);  // 16 MB @ 20 MB
  unsigned short* Wh = (unsigned short*)(ws + 37748736);  // 2 MB  @ 36 MB

  hipMemsetAsync(ws, 0, 17408, stream);                   // loss + hist
  vq_split<<<2304, 256, 0, stream>>>(Z, W, Zh, Wh);
  vq_rownorm<<<NROWS / 4, 256, 0, stream>>>(Z, anorm);
  vq_mfma<<<8192, 256, 0, stream>>>(Zh, Wh, anorm, partial);
  vq_tail<<<NROWS / 4, 256, 0, stream>>>(Z, W, anorm, partial, zq_out, idx_out, loss_acc, hist);
  vq_final<<<1, 64, 0, stream>>>(loss_acc, hist, scal);
}

// Round 10
// 299.714 us; speedup vs baseline: 1.7464x; 1.1053x over previous
//
#include <hip/hip_runtime.h>
#include <math.h>

constexpr int NROWS = 32768;   // B
constexpr int DIMC  = 256;     // D
constexpr int KC    = 4096;    // K

typedef __attribute__((ext_vector_type(8))) short short8;
typedef __attribute__((ext_vector_type(4))) float f32x4;

#define AS1 __attribute__((address_space(1)))
#define AS3 __attribute__((address_space(3)))

struct alignas(16) Part { float d1; int i1; float d2; int i2; };

// ambiguity window: validated r7 (~15 sigma of h-only bf16 approx error)
#define WIN 3.0e-4f

__device__ __forceinline__ unsigned short f2bf(float x) {
  unsigned u = __float_as_uint(x);
  return (unsigned short)((u + 0x7fffu + ((u >> 16) & 1u)) >> 16);
}

// ---------------------------------------------------------------------------
// Fused split: h-plane bf16 in the GEMM's tiled, swizzled HBM layout
// [blk128][kblk(8)][granule g=r*4+slot], slot holds octet s8=slot^((r>>1)&3).
// bid < 2048 -> Z tiles; bid 2048..2303 -> W tiles. (layout validated r3-r9)
// ---------------------------------------------------------------------------
__global__ __launch_bounds__(256)
void vq_split(const float* __restrict__ Z, const float* __restrict__ W,
              unsigned short* __restrict__ Zh, unsigned short* __restrict__ Wh) {
  const bool isW = blockIdx.x >= 2048;
  const int bid  = isW ? (blockIdx.x - 2048) : blockIdx.x;
  const float* X = isW ? W : Z;
  unsigned short* out = isW ? Wh : Zh;
  const int blk = bid >> 3;
  const int kb  = bid & 7;
  const int t = threadIdx.x;
#pragma unroll
  for (int gi = 0; gi < 2; ++gi) {
    const int g = t + gi * 256;
    const int r = g >> 2, slot = g & 3;
    const int s8 = slot ^ ((r >> 1) & 3);
    const float* src = X + (size_t)(blk * 128 + r) * DIMC + kb * 32 + s8 * 8;
    short8 vh;
#pragma unroll
    for (int j = 0; j < 8; ++j) vh[j] = (short)f2bf(src[j]);
    *(short8*)(out + ((size_t)blk * 8 + kb) * 4096 + g * 8) = vh;
  }
}

// ---------------------------------------------------------------------------
__global__ __launch_bounds__(256)
void vq_rownorm(const float* __restrict__ Z, float* __restrict__ anorm) {
  const int lane = threadIdx.x & 63;
  const int wv   = threadIdx.x >> 6;
  const int row  = blockIdx.x * 4 + wv;
  const float4 z4 = *(const float4*)(Z + (size_t)row * DIMC + lane * 4);
  double s = (double)z4.x * z4.x + (double)z4.y * z4.y +
             (double)z4.z * z4.z + (double)z4.w * z4.w;
#pragma unroll
  for (int off = 32; off > 0; off >>= 1) s += __shfl_down(s, off);
  if (lane == 0) anorm[row] = (float)s;
}

// ---------------------------------------------------------------------------
// Main: h-only bf16 MFMA GEMM, LDS staging (global_load_lds, conflict-free
// swizzle) + u32-key DPP top-2 epilogue. (validated r9)
// ---------------------------------------------------------------------------
#define DPP_STAGE(CTRL)                                                        \
  {                                                                            \
    unsigned n1 = (unsigned)__builtin_amdgcn_update_dpp((int)k1, (int)k1,      \
                                                        CTRL, 0xF, 0xF, false);\
    unsigned n2 = (unsigned)__builtin_amdgcn_update_dpp((int)k2, (int)k2,      \
                                                        CTRL, 0xF, 0xF, false);\
    const unsigned tmax = max(k1, n1);                                         \
    k1 = min(k1, n1);                                                          \
    k2 = min(min(k2, n2), tmax);                                               \
  }

__global__ __launch_bounds__(256, 4)
void vq_mfma(const unsigned short* __restrict__ Zh, const unsigned short* __restrict__ Wh,
             const float* __restrict__ anorm, Part* __restrict__ partial) {
  __shared__ char lds[16384];          // A: [0,8K), B: [8K,16K)
  const int t = threadIdx.x, lane = t & 63, w = t >> 6;
  const int rb = blockIdx.x >> 5, cb = blockIdx.x & 31;
  const int q = lane >> 4, ml = lane & 15;
  const int wr = w >> 1, wc = w & 1;

  const unsigned short* src0 = (w < 2) ? Zh + (size_t)rb * 32768
                                       : Wh + (size_t)cb * 32768;
  const int half = w & 1;
  char* ldsdst = lds + (w >> 1) * 8192 + half * 4096;

  int aoff[4], boff[4];
#pragma unroll
  for (int i = 0; i < 4; ++i) {
    const int r = wr * 64 + i * 16 + ml;
    aoff[i] = (r * 4 + (q ^ ((r >> 1) & 3))) * 16;
    const int c = wc * 64 + i * 16 + ml;
    boff[i] = (c * 4 + (q ^ ((c >> 1) & 3))) * 16;
  }

  f32x4 acc[4][4];
#pragma unroll
  for (int i = 0; i < 4; ++i)
#pragma unroll
    for (int j = 0; j < 4; ++j) acc[i][j] = (f32x4){0.f, 0.f, 0.f, 0.f};

  for (int kb = 0; kb < 8; ++kb) {
    __syncthreads();
    const unsigned short* s = src0 + kb * 4096 + half * 2048 + lane * 8;
#pragma unroll
    for (int i = 0; i < 4; ++i)
      __builtin_amdgcn_global_load_lds((const AS1 void*)(s + i * 512),
                                       (AS3 void*)(ldsdst + i * 1024), 16, 0, 0);
    __syncthreads();
    short8 Ah[4], Bh[4];
#pragma unroll
    for (int i = 0; i < 4; ++i) {
      Ah[i] = *(const short8*)(lds +        aoff[i]);
      Bh[i] = *(const short8*)(lds + 8192 + boff[i]);
    }
#pragma unroll
    for (int i = 0; i < 4; ++i)
#pragma unroll
      for (int j = 0; j < 4; ++j)
        acc[i][j] = __builtin_amdgcn_mfma_f32_16x16x32_bf16(Ah[i], Bh[j], acc[i][j], 0, 0, 0);
  }

  // ------ key-based epilogue ------
  __syncthreads();                      // LDS reuse for per-wave results
  uint2* pk = (uint2*)lds;              // [4 waves][64 rows]
  const float SC = 33554432.0f;         // 2^25; |acc| < 0.06 -> 0.125-acc in (0,0.25)

#pragma unroll
  for (int i = 0; i < 4; ++i) {
#pragma unroll
    for (int r = 0; r < 4; ++r) {
      unsigned k[4];
#pragma unroll
      for (int j = 0; j < 4; ++j) {
        const unsigned qv = (unsigned)((0.125f - acc[i][j][r]) * SC);
        k[j] = (qv << 7) | (unsigned)(wc * 64 + j * 16 + ml);
      }
      const unsigned m01 = min(k[0], k[1]), x01 = max(k[0], k[1]);
      const unsigned m23 = min(k[2], k[3]), x23 = max(k[2], k[3]);
      unsigned k1 = min(m01, m23);
      unsigned k2 = min(min(x01, x23), max(m01, m23));
      DPP_STAGE(0x121)   // row_ror:1
      DPP_STAGE(0x122)   // row_ror:2
      DPP_STAGE(0x124)   // row_ror:4
      DPP_STAGE(0x128)   // row_ror:8
      if (ml == 0) pk[w * 64 + (i * 16 + q * 4 + r)] = make_uint2(k1, k2);
    }
  }
  __syncthreads();
  if (t < 128) {
    const int wrh = t >> 6, lr = t & 63;
    const uint2 A2 = pk[(wrh * 2 + 0) * 64 + lr];
    const uint2 B2 = pk[(wrh * 2 + 1) * 64 + lr];
    const unsigned k1 = min(A2.x, B2.x);
    const unsigned k2 = min(min(A2.y, B2.y), max(A2.x, B2.x));
    const int row = rb * 128 + wrh * 64 + lr;
    const float am = anorm[row];
    const float inv = 2.9802322387695312e-08f;   // 2^-25
    const float dot1 = 0.125f - (float)(k1 >> 7) * inv;
    const float dot2 = 0.125f - (float)(k2 >> 7) * inv;
    Part p;
    p.d1 = am - 2.0f * dot1;
    p.i1 = cb * 128 + (int)(k1 & 127u);
    p.d2 = am - 2.0f * dot2;
    p.i2 = 0;
    partial[(size_t)row * 32 + cb] = p;
  }
}

// ---------------------------------------------------------------------------
// Exact np-semantics distance (byte-identical chain to rounds 2-9).
// ---------------------------------------------------------------------------
__device__ __forceinline__ float exact_d(const float* __restrict__ Z,
                                         const float* __restrict__ W,
                                         int row, int c, float a) {
  const float* z = Z + (size_t)row * DIMC;
  const float* w = W + (size_t)c * DIMC;
  float dot = 0.f;
  for (int d0 = 0; d0 < DIMC; d0 += 4) {
    const float4 zv = *(const float4*)(z + d0);
    const float4 wv = *(const float4*)(w + d0);
    dot = fmaf(zv.x, wv.x, dot);
    dot = fmaf(zv.y, wv.y, dot);
    dot = fmaf(zv.z, wv.z, dot);
    dot = fmaf(zv.w, wv.w, dot);
  }
  return a - 2.0f * dot;
}

// ---------------------------------------------------------------------------
// Fused tail: merge partials, WIN-gated exact resolve, gather z_q, indices,
// f64 loss partial (PER-BLOCK STORE — no same-address atomic) + histogram.
// ---------------------------------------------------------------------------
__global__ __launch_bounds__(256)
void vq_tail(const float* __restrict__ Z, const float* __restrict__ W,
             const float* __restrict__ anorm, const Part* __restrict__ partial,
             float* __restrict__ zq_out, float* __restrict__ idx_out,
             double* __restrict__ lossp, int* __restrict__ hist) {
  __shared__ double sh[4];
  const int lane = threadIdx.x & 63, wv = threadIdx.x >> 6;
  const int row = blockIdx.x * 4 + wv;
  const float INF = 3.4e38f;

  float d1 = INF, d2 = INF; int i1 = 0x7fffffff;
  if (lane < 32) {
    const Part p = partial[(size_t)row * 32 + lane];
    d1 = p.d1; d2 = p.d2; i1 = p.i1;
  }
  float g1 = d1, g2 = d2; int gi = i1;
#pragma unroll
  for (int mask = 1; mask < 32; mask <<= 1) {
    const float og1 = __shfl_xor(g1, mask);
    const int   ogi = __shfl_xor(gi, mask);
    const float og2 = __shfl_xor(g2, mask);
    if (og1 < g1 || (og1 == g1 && ogi < gi)) {
      g2 = fminf(g1, og2); g1 = og1; gi = ogi;
    } else g2 = fminf(g2, og1);
  }
  g1 = __shfl(g1, 0); g2 = __shfl(g2, 0); gi = __shfl(gi, 0);

  int k;
  if (g2 - g1 > WIN) {
    k = gi;
  } else {
    const float a = anorm[row];
    const float thr = g1 + WIN;
    const bool scan   = (lane < 32) && (d2 <= thr);
    const bool single = (lane < 32) && !scan && (d1 <= thr);
    float bd = INF; int bi = 0x7fffffff;
    if (single) {
      const float d = exact_d(Z, W, row, i1, a);
      if (d < bd || (d == bd && i1 < bi)) { bd = d; bi = i1; }
    }
    unsigned long long msk = __ballot(scan);
    while (msk) {
      const int cbk = __ffsll(msk) - 1; msk &= msk - 1;
#pragma unroll
      for (int h = 0; h < 2; ++h) {
        const int c = cbk * 128 + h * 64 + lane;
        const float d = exact_d(Z, W, row, c, a);
        if (d < bd || (d == bd && c < bi)) { bd = d; bi = c; }
      }
    }
#pragma unroll
    for (int mask = 1; mask < 64; mask <<= 1) {
      const float od = __shfl_xor(bd, mask);
      const int   oi = __shfl_xor(bi, mask);
      if (od < bd || (od == bd && oi < bi)) { bd = od; bi = oi; }
    }
    k = bi;
  }

  const float4 z4 = *(const float4*)(Z + (size_t)row * DIMC + lane * 4);
  const float4 w4 = *(const float4*)(W + (size_t)k   * DIMC + lane * 4);
  *(float4*)(zq_out + (size_t)row * DIMC + lane * 4) = w4;

  const double dx = (double)w4.x - (double)z4.x;
  const double dy = (double)w4.y - (double)z4.y;
  const double dz = (double)w4.z - (double)z4.z;
  const double dw = (double)w4.w - (double)z4.w;
  double l = dx * dx + dy * dy + dz * dz + dw * dw;
#pragma unroll
  for (int off = 32; off > 0; off >>= 1) l += __shfl_down(l, off);

  if (lane == 0) { sh[wv] = l; idx_out[row] = (float)k; atomicAdd(&hist[k], 1); }
  __syncthreads();
  if (threadIdx.x == 0) lossp[blockIdx.x] = sh[0] + sh[1] + sh[2] + sh[3];
}

// ---------------------------------------------------------------------------
// Final: sum per-block loss partials (8192 f64) + entropy -> scalars.
// ---------------------------------------------------------------------------
__global__ __launch_bounds__(64)
void vq_final(const double* __restrict__ lossp, const int* __restrict__ hist,
              float* __restrict__ scal) {
  const int lane = threadIdx.x;
  double L = 0.0;
  for (int i = lane; i < NROWS / 4; i += 64) L += lossp[i];
  double H = 0.0;
  for (int k = lane; k < KC; k += 64) {
    const double p = (double)hist[k] / (double)NROWS;
    H -= p * log(p + 1e-10);
  }
#pragma unroll
  for (int off = 32; off > 0; off >>= 1) {
    L += __shfl_down(L, off);
    H += __shfl_down(H, off);
  }
  if (lane == 0) {
    scal[0] = (float)(L * 1.25 / ((double)NROWS * (double)DIMC));
    scal[1] = (float)exp(H);
  }
}

// ---------------------------------------------------------------------------
extern "C" void kernel_launch(void* const* d_in, const int* in_sizes, int n_in,
                              void* d_out, int out_size, void* d_ws, size_t ws_size,
                              hipStream_t stream) {
  const float* Z = (const float*)d_in[0];
  const float* W = (const float*)d_in[1];
  float* out = (float*)d_out;
  float* zq_out  = out;
  float* idx_out = out + (size_t)NROWS * DIMC;
  float* scal    = idx_out + NROWS;

  char* ws = (char*)d_ws;
  int*    hist       = (int*)(ws + 1024);                 // 16 KB
  double* lossp      = (double*)(ws + 32768);             // 64 KB (8192 f64)
  float*  anorm      = (float*)(ws + 163840);             // 128 KB
  Part*   partial    = (Part*)(ws + 1048576);             // 16 MB @ 1 MB
  unsigned short* Zh = (unsigned short*)(ws + 20971520);  // 16 MB @ 20 MB
  unsigned short* Wh = (unsigned short*)(ws + 37748736);  // 2 MB  @ 36 MB

  hipMemsetAsync(ws, 0, 17408, stream);                   // hist
  vq_split<<<2304, 256, 0, stream>>>(Z, W, Zh, Wh);
  vq_rownorm<<<NROWS / 4, 256, 0, stream>>>(Z, anorm);
  vq_mfma<<<8192, 256, 0, stream>>>(Zh, Wh, anorm, partial);
  vq_tail<<<NROWS / 4, 256, 0, stream>>>(Z, W, anorm, partial, zq_out, idx_out, lossp, hist);
  vq_final<<<1, 64, 0, stream>>>(lossp, hist, scal);
}

// Round 11
// 295.307 us; speedup vs baseline: 1.7725x; 1.0149x over previous
//
#include <hip/hip_runtime.h>
#include <math.h>

constexpr int NROWS = 32768;   // B
constexpr int DIMC  = 256;     // D
constexpr int KC    = 4096;    // K

typedef __attribute__((ext_vector_type(8))) short short8;
typedef __attribute__((ext_vector_type(4))) float f32x4;

#define AS1 __attribute__((address_space(1)))
#define AS3 __attribute__((address_space(3)))

// ambiguity window (validated r7-r10): WIN = 3e-4 in d-units.
// integer q-units: 1 q = 2^-21 in d  ->  630 q ~= 3.004e-4.
#define WIN      3.0e-4f
#define WINQ     630u
#define Q2D      4.76837158203125e-07f   // 2^-21

__device__ __forceinline__ unsigned short f2bf(float x) {
  unsigned u = __float_as_uint(x);
  return (unsigned short)((u + 0x7fffu + ((u >> 16) & 1u)) >> 16);
}

// ---------------------------------------------------------------------------
// Fused pre-pass: bf16 h-plane in the GEMM's tiled swizzled layout
// (validated r3-r10: zero LDS bank conflicts downstream) + per-row fp32(f64)
// norms for Z. Blocks 0..255 -> Z tiles (full row coverage -> norms);
// blocks 256..287 -> W tiles.
// ---------------------------------------------------------------------------
__global__ __launch_bounds__(256)
void vq_prep(const float* __restrict__ Z, const float* __restrict__ W,
             unsigned short* __restrict__ Zh, unsigned short* __restrict__ Wh,
             float* __restrict__ anorm) {
  const bool isW = blockIdx.x >= 256;
  const int blk  = isW ? ((int)blockIdx.x - 256) : (int)blockIdx.x;
  const float* X = isW ? W : Z;
  unsigned short* out = isW ? Wh : Zh;
  const int t = threadIdx.x;

  double ps[2] = {0.0, 0.0};
  for (int kb = 0; kb < 8; ++kb) {
#pragma unroll
    for (int gi = 0; gi < 2; ++gi) {
      const int g = t + gi * 256;
      const int r = g >> 2, slot = g & 3;
      const int s8 = slot ^ ((r >> 1) & 3);
      const float* src = X + (size_t)(blk * 128 + r) * DIMC + kb * 32 + s8 * 8;
      short8 vh;
      double s = 0.0;
#pragma unroll
      for (int j = 0; j < 8; ++j) {
        const float x = src[j];
        vh[j] = (short)f2bf(x);
        s += (double)x * x;
      }
      *(short8*)(out + ((size_t)blk * 8 + kb) * 4096 + g * 8) = vh;
      ps[gi] += s;
    }
  }
  if (!isW) {
    __shared__ double sn[512];
    sn[t] = ps[0]; sn[256 + t] = ps[1];
    __syncthreads();
    if (t < 128) {
      double s;
      if (t < 64) s = sn[4 * t] + sn[4 * t + 1] + sn[4 * t + 2] + sn[4 * t + 3];
      else {
        const int r1 = t - 64;
        s = sn[256 + 4 * r1] + sn[256 + 4 * r1 + 1] +
            sn[256 + 4 * r1 + 2] + sn[256 + 4 * r1 + 3];
      }
      anorm[blk * 128 + t] = (float)s;
    }
  }
}

// ---------------------------------------------------------------------------
// Main GEMM: h-only bf16 MFMA, BK=64 (two 8KB k-sections per barrier pair ->
// 8 barriers/block instead of 16), 32 KB LDS, 4 blocks/CU.
// Epilogue: u32-key DPP top-2 (validated r9/r10), now emitting GLOBAL keys:
// key = q20 << 12 | cb << 7 | col7  (q20 = (0.125-acc)*2^22, trunc; argmin(d)
// == argmin(key), ties -> lower global index == np first-min).
// ---------------------------------------------------------------------------
#define DPP_STAGE(CTRL)                                                        \
  {                                                                            \
    unsigned n1 = (unsigned)__builtin_amdgcn_update_dpp((int)k1, (int)k1,      \
                                                        CTRL, 0xF, 0xF, false);\
    unsigned n2 = (unsigned)__builtin_amdgcn_update_dpp((int)k2, (int)k2,      \
                                                        CTRL, 0xF, 0xF, false);\
    const unsigned tmax = max(k1, n1);                                         \
    k1 = min(k1, n1);                                                          \
    k2 = min(min(k2, n2), tmax);                                               \
  }

__global__ __launch_bounds__(256, 4)
void vq_mfma(const unsigned short* __restrict__ Zh, const unsigned short* __restrict__ Wh,
             uint2* __restrict__ partial) {
  __shared__ char lds[32768];          // A: [0,16K) sec0/sec1; B: [16K,32K)
  const int t = threadIdx.x, lane = t & 63, w = t >> 6;
  const int rb = blockIdx.x >> 5, cb = blockIdx.x & 31;
  const int q = lane >> 4, ml = lane & 15;
  const int wr = w >> 1, wc = w & 1;

  const unsigned short* src0 = (w < 2) ? Zh + (size_t)rb * 32768
                                       : Wh + (size_t)cb * 32768;
  const int half = w & 1;
  char* base_dst = lds + (w >> 1) * 16384 + half * 4096;

  int aoff[4], boff[4];
#pragma unroll
  for (int i = 0; i < 4; ++i) {
    const int r = wr * 64 + i * 16 + ml;
    aoff[i] = (r * 4 + (q ^ ((r >> 1) & 3))) * 16;
    const int c = wc * 64 + i * 16 + ml;
    boff[i] = (c * 4 + (q ^ ((c >> 1) & 3))) * 16;
  }

  f32x4 acc[4][4];
#pragma unroll
  for (int i = 0; i < 4; ++i)
#pragma unroll
    for (int j = 0; j < 4; ++j) acc[i][j] = (f32x4){0.f, 0.f, 0.f, 0.f};

  for (int kb2 = 0; kb2 < 4; ++kb2) {
    __syncthreads();
#pragma unroll
    for (int sec = 0; sec < 2; ++sec) {
      const unsigned short* s = src0 + (kb2 * 2 + sec) * 4096 + half * 2048 + lane * 8;
#pragma unroll
      for (int i = 0; i < 4; ++i)
        __builtin_amdgcn_global_load_lds((const AS1 void*)(s + i * 512),
                                         (AS3 void*)(base_dst + sec * 8192 + i * 1024),
                                         16, 0, 0);
    }
    __syncthreads();
#pragma unroll
    for (int sec = 0; sec < 2; ++sec) {
      short8 Ah[4], Bh[4];
#pragma unroll
      for (int i = 0; i < 4; ++i) {
        Ah[i] = *(const short8*)(lds +         sec * 8192 + aoff[i]);
        Bh[i] = *(const short8*)(lds + 16384 + sec * 8192 + boff[i]);
      }
#pragma unroll
      for (int i = 0; i < 4; ++i)
#pragma unroll
        for (int j = 0; j < 4; ++j)
          acc[i][j] = __builtin_amdgcn_mfma_f32_16x16x32_bf16(Ah[i], Bh[j], acc[i][j], 0, 0, 0);
    }
  }

  // ------ global u32-key epilogue ------
  __syncthreads();                      // LDS reuse
  uint2* pk = (uint2*)lds;              // [4 waves][64 rows]
  const float SC = 4194304.0f;          // 2^22; (0.125-acc) in (0.05,0.20) -> q20 < 2^20

#pragma unroll
  for (int i = 0; i < 4; ++i) {
#pragma unroll
    for (int r = 0; r < 4; ++r) {
      unsigned k[4];
#pragma unroll
      for (int j = 0; j < 4; ++j) {
        const unsigned qv = (unsigned)((0.125f - acc[i][j][r]) * SC);
        k[j] = (qv << 7) | (unsigned)(wc * 64 + j * 16 + ml);
      }
      const unsigned m01 = min(k[0], k[1]), x01 = max(k[0], k[1]);
      const unsigned m23 = min(k[2], k[3]), x23 = max(k[2], k[3]);
      unsigned k1 = min(m01, m23);
      unsigned k2 = min(min(x01, x23), max(m01, m23));
      DPP_STAGE(0x121)   // row_ror:1
      DPP_STAGE(0x122)   // row_ror:2
      DPP_STAGE(0x124)   // row_ror:4
      DPP_STAGE(0x128)   // row_ror:8
      if (ml == 0) pk[w * 64 + (i * 16 + q * 4 + r)] = make_uint2(k1, k2);
    }
  }
  __syncthreads();
  if (t < 128) {
    const int wrh = t >> 6, lr = t & 63;
    const uint2 A2 = pk[(wrh * 2 + 0) * 64 + lr];
    const uint2 B2 = pk[(wrh * 2 + 1) * 64 + lr];
    const unsigned k1 = min(A2.x, B2.x);
    const unsigned k2 = min(min(A2.y, B2.y), max(A2.x, B2.x));
    const unsigned g1 = ((k1 >> 7) << 12) | ((unsigned)cb << 7) | (k1 & 127u);
    const unsigned g2 = ((k2 >> 7) << 12) | ((unsigned)cb << 7) | (k2 & 127u);
    const int row = rb * 128 + wrh * 64 + lr;
    partial[(size_t)row * 32 + cb] = make_uint2(g1, g2);
  }
}

// ---------------------------------------------------------------------------
// Exact np-semantics distance (byte-identical chain to rounds 2-10).
// ---------------------------------------------------------------------------
__device__ __forceinline__ float exact_d(const float* __restrict__ Z,
                                         const float* __restrict__ W,
                                         int row, int c, float a) {
  const float* z = Z + (size_t)row * DIMC;
  const float* w = W + (size_t)c * DIMC;
  float dot = 0.f;
  for (int d0 = 0; d0 < DIMC; d0 += 4) {
    const float4 zv = *(const float4*)(z + d0);
    const float4 wv = *(const float4*)(w + d0);
    dot = fmaf(zv.x, wv.x, dot);
    dot = fmaf(zv.y, wv.y, dot);
    dot = fmaf(zv.z, wv.z, dot);
    dot = fmaf(zv.w, wv.w, dot);
  }
  return a - 2.0f * dot;
}

// ---------------------------------------------------------------------------
// Fused tail: pure-u32 merge of 32 per-colblock key pairs, integer WIN gate,
// exact resolve for ambiguous rows, gather z_q, indices, per-block f64 loss
// partial store + histogram.
// ---------------------------------------------------------------------------
__global__ __launch_bounds__(256)
void vq_tail(const float* __restrict__ Z, const float* __restrict__ W,
             const float* __restrict__ anorm, const uint2* __restrict__ partial,
             float* __restrict__ zq_out, float* __restrict__ idx_out,
             double* __restrict__ lossp, int* __restrict__ hist) {
  __shared__ double sh[4];
  const int lane = threadIdx.x & 63, wv = threadIdx.x >> 6;
  const int row = blockIdx.x * 4 + wv;
  const float INF = 3.4e38f;

  unsigned k1 = 0xFFFFFFFFu, k2 = 0xFFFFFFFFu;
  if (lane < 32) {
    const uint2 p = partial[(size_t)row * 32 + lane];
    k1 = p.x; k2 = p.y;
  }
  unsigned g1 = k1, g2 = k2;
#pragma unroll
  for (int mask = 1; mask < 32; mask <<= 1) {
    const unsigned og1 = (unsigned)__shfl_xor((int)g1, mask);
    const unsigned og2 = (unsigned)__shfl_xor((int)g2, mask);
    const unsigned mx = max(g1, og1);
    g1 = min(g1, og1);
    g2 = min(min(g2, og2), mx);
  }
  g1 = (unsigned)__shfl((int)g1, 0);
  g2 = (unsigned)__shfl((int)g2, 0);

  int k;
  const unsigned q1 = g1 >> 12;
  if ((g2 >> 12) - q1 > WINQ) {
    k = (int)(g1 & 4095u);
  } else {
    const float a = anorm[row];
    const float thr = (a - 0.25f + (float)q1 * Q2D) + WIN;
    const bool scan   = (lane < 32) && ((k2 >> 12) <= q1 + WINQ);
    const bool single = (lane < 32) && !scan && ((k1 >> 12) <= q1 + WINQ);
    float bd = INF; int bi = 0x7fffffff;
    if (single) {
      const int c = (int)(k1 & 4095u);
      const float d = exact_d(Z, W, row, c, a);
      if (d < bd || (d == bd && c < bi)) { bd = d; bi = c; }
    }
    unsigned long long msk = __ballot(scan);
    while (msk) {
      const int cbk = __ffsll(msk) - 1; msk &= msk - 1;
#pragma unroll
      for (int h = 0; h < 2; ++h) {
        const int c = cbk * 128 + h * 64 + lane;
        const float d = exact_d(Z, W, row, c, a);
        if (d < bd || (d == bd && c < bi)) { bd = d; bi = c; }
      }
    }
#pragma unroll
    for (int mask = 1; mask < 64; mask <<= 1) {
      const float od = __shfl_xor(bd, mask);
      const int   oi = __shfl_xor(bi, mask);
      if (od < bd || (od == bd && oi < bi)) { bd = od; bi = oi; }
    }
    // thr unused beyond gating candidate set; bd/bi hold the exact argmin
    (void)thr;
    k = bi;
  }

  const float4 z4 = *(const float4*)(Z + (size_t)row * DIMC + lane * 4);
  const float4 w4 = *(const float4*)(W + (size_t)k   * DIMC + lane * 4);
  *(float4*)(zq_out + (size_t)row * DIMC + lane * 4) = w4;

  const double dx = (double)w4.x - (double)z4.x;
  const double dy = (double)w4.y - (double)z4.y;
  const double dz = (double)w4.z - (double)z4.z;
  const double dw = (double)w4.w - (double)z4.w;
  double l = dx * dx + dy * dy + dz * dz + dw * dw;
#pragma unroll
  for (int off = 32; off > 0; off >>= 1) l += __shfl_down(l, off);

  if (lane == 0) { sh[wv] = l; idx_out[row] = (float)k; atomicAdd(&hist[k], 1); }
  __syncthreads();
  if (threadIdx.x == 0) lossp[blockIdx.x] = sh[0] + sh[1] + sh[2] + sh[3];
}

// ---------------------------------------------------------------------------
// Final: sum per-block loss partials + entropy -> scalars.
// ---------------------------------------------------------------------------
__global__ __launch_bounds__(64)
void vq_final(const double* __restrict__ lossp, const int* __restrict__ hist,
              float* __restrict__ scal) {
  const int lane = threadIdx.x;
  double L = 0.0;
  for (int i = lane; i < NROWS / 4; i += 64) L += lossp[i];
  double H = 0.0;
  for (int k = lane; k < KC; k += 64) {
    const double p = (double)hist[k] / (double)NROWS;
    H -= p * log(p + 1e-10);
  }
#pragma unroll
  for (int off = 32; off > 0; off >>= 1) {
    L += __shfl_down(L, off);
    H += __shfl_down(H, off);
  }
  if (lane == 0) {
    scal[0] = (float)(L * 1.25 / ((double)NROWS * (double)DIMC));
    scal[1] = (float)exp(H);
  }
}

// ---------------------------------------------------------------------------
extern "C" void kernel_launch(void* const* d_in, const int* in_sizes, int n_in,
                              void* d_out, int out_size, void* d_ws, size_t ws_size,
                              hipStream_t stream) {
  const float* Z = (const float*)d_in[0];
  const float* W = (const float*)d_in[1];
  float* out = (float*)d_out;
  float* zq_out  = out;
  float* idx_out = out + (size_t)NROWS * DIMC;
  float* scal    = idx_out + NROWS;

  char* ws = (char*)d_ws;
  int*    hist       = (int*)(ws + 1024);                 // 16 KB
  float*  anorm      = (float*)(ws + 163840);             // 128 KB
  double* lossp      = (double*)(ws + 524288);            // 64 KB (8192 f64)
  uint2*  partial    = (uint2*)(ws + 1048576);            // 8 MB @ 1 MB
  unsigned short* Zh = (unsigned short*)(ws + 20971520);  // 16 MB @ 20 MB
  unsigned short* Wh = (unsigned short*)(ws + 37748736);  // 2 MB  @ 36 MB

  hipMemsetAsync(ws, 0, 17408, stream);                   // hist
  vq_prep<<<288, 256, 0, stream>>>(Z, W, Zh, Wh, anorm);
  vq_mfma<<<8192, 256, 0, stream>>>(Zh, Wh, partial);
  vq_tail<<<NROWS / 4, 256, 0, stream>>>(Z, W, anorm, partial, zq_out, idx_out, lossp, hist);
  vq_final<<<1, 64, 0, stream>>>(lossp, hist, scal);
}

// Round 12
// 292.336 us; speedup vs baseline: 1.7905x; 1.0102x over previous
//
#include <hip/hip_runtime.h>
#include <math.h>

constexpr int NROWS = 32768;   // B
constexpr int DIMC  = 256;     // D
constexpr int KC    = 4096;    // K

typedef __attribute__((ext_vector_type(8))) short short8;
typedef __attribute__((ext_vector_type(4))) float f32x4;

#define AS1 __attribute__((address_space(1)))
#define AS3 __attribute__((address_space(3)))

// ambiguity window (validated r7-r11): WIN = 3e-4 in d-units; 630 q (q=2^-21).
#define WIN      3.0e-4f
#define WINQ     630u

__device__ __forceinline__ unsigned short f2bf(float x) {
  unsigned u = __float_as_uint(x);
  return (unsigned short)((u + 0x7fffu + ((u >> 16) & 1u)) >> 16);
}

// ---------------------------------------------------------------------------
// Pre-pass (convert-only): bf16 h-plane in the tiled swizzled layout
// (validated r3-r11). 1152 blocks: bid<1024 -> Z (blk=bid>>2, 2 kb each);
// else W. No norms here (tail computes them in-wave).
// ---------------------------------------------------------------------------
__global__ __launch_bounds__(256)
void vq_prep(const float* __restrict__ Z, const float* __restrict__ W,
             unsigned short* __restrict__ Zh, unsigned short* __restrict__ Wh) {
  const bool isW = blockIdx.x >= 1024;
  const int bid  = isW ? ((int)blockIdx.x - 1024) : (int)blockIdx.x;
  const float* X = isW ? W : Z;
  unsigned short* out = isW ? Wh : Zh;
  const int blk = bid >> 2;
  const int kb0 = (bid & 3) * 2;
  const int t = threadIdx.x;

#pragma unroll
  for (int kk = 0; kk < 2; ++kk) {
    const int kb = kb0 + kk;
#pragma unroll
    for (int gi = 0; gi < 2; ++gi) {
      const int g = t + gi * 256;
      const int r = g >> 2, slot = g & 3;
      const int s8 = slot ^ ((r >> 1) & 3);
      const float* src = X + (size_t)(blk * 128 + r) * DIMC + kb * 32 + s8 * 8;
      short8 vh;
#pragma unroll
      for (int j = 0; j < 8; ++j) vh[j] = (short)f2bf(src[j]);
      *(short8*)(out + ((size_t)blk * 8 + kb) * 4096 + g * 8) = vh;
    }
  }
}

// ---------------------------------------------------------------------------
// Main GEMM: h-only bf16 MFMA. A fragments loaded DIRECTLY from the swizzled
// global layout (each frag = contiguous coalesced 1 KB; L1/L2-resident).
// Only B staged through LDS (16 KB, 4 KB per wave per BK=64), 8 barriers.
// Epilogue: u32 global-key DPP top-2 (validated r9-r11).
// ---------------------------------------------------------------------------
#define DPP_STAGE(CTRL)                                                        \
  {                                                                            \
    unsigned n1 = (unsigned)__builtin_amdgcn_update_dpp((int)k1, (int)k1,      \
                                                        CTRL, 0xF, 0xF, false);\
    unsigned n2 = (unsigned)__builtin_amdgcn_update_dpp((int)k2, (int)k2,      \
                                                        CTRL, 0xF, 0xF, false);\
    const unsigned tmax = max(k1, n1);                                         \
    k1 = min(k1, n1);                                                          \
    k2 = min(min(k2, n2), tmax);                                               \
  }

__global__ __launch_bounds__(256, 4)
void vq_mfma(const unsigned short* __restrict__ Zh, const unsigned short* __restrict__ Wh,
             uint2* __restrict__ partial) {
  __shared__ char lds[16384];          // B: sec0 [0,8K), sec1 [8K,16K)
  const int t = threadIdx.x, lane = t & 63, w = t >> 6;
  const int rb = blockIdx.x >> 5, cb = blockIdx.x & 31;
  const int q = lane >> 4, ml = lane & 15;
  const int wr = w >> 1, wc = w & 1;

  // B staging: wave w covers sec = w>>1, half = w&1 (4 KB each per BK=64)
  const unsigned short* bsrc = Wh + (size_t)cb * 32768 + (w >> 1) * 4096
                             + (w & 1) * 2048 + lane * 8;
  char* bdst = lds + (w >> 1) * 8192 + (w & 1) * 4096;

  int aoff[4], boff[4];
#pragma unroll
  for (int i = 0; i < 4; ++i) {
    const int r = wr * 64 + i * 16 + ml;
    aoff[i] = (r * 4 + (q ^ ((r >> 1) & 3))) * 16;
    const int c = wc * 64 + i * 16 + ml;
    boff[i] = (c * 4 + (q ^ ((c >> 1) & 3))) * 16;
  }
  const char* Abase = (const char*)Zh + (size_t)rb * 65536;   // 8 kb x 8192 B

  f32x4 acc[4][4];
#pragma unroll
  for (int i = 0; i < 4; ++i)
#pragma unroll
    for (int j = 0; j < 4; ++j) acc[i][j] = (f32x4){0.f, 0.f, 0.f, 0.f};

  for (int kb2 = 0; kb2 < 4; ++kb2) {
    __syncthreads();
    // issue B staging DMA (4 x 1 KB per wave)
#pragma unroll
    for (int i = 0; i < 4; ++i)
      __builtin_amdgcn_global_load_lds((const AS1 void*)(bsrc + kb2 * 8192 + i * 512),
                                       (AS3 void*)(bdst + i * 1024), 16, 0, 0);
    // A-direct fragment loads for both secs (overlap staging latency)
    short8 Af[2][4];
#pragma unroll
    for (int sec = 0; sec < 2; ++sec) {
      const int kb = kb2 * 2 + sec;
#pragma unroll
      for (int i = 0; i < 4; ++i)
        Af[sec][i] = *(const short8*)(Abase + (size_t)kb * 8192 + aoff[i]);
    }
    __syncthreads();
#pragma unroll
    for (int sec = 0; sec < 2; ++sec) {
      short8 Bf[4];
#pragma unroll
      for (int i = 0; i < 4; ++i)
        Bf[i] = *(const short8*)(lds + sec * 8192 + boff[i]);
#pragma unroll
      for (int i = 0; i < 4; ++i)
#pragma unroll
        for (int j = 0; j < 4; ++j)
          acc[i][j] = __builtin_amdgcn_mfma_f32_16x16x32_bf16(Af[sec][i], Bf[j], acc[i][j], 0, 0, 0);
    }
  }

  // ------ global u32-key epilogue (validated) ------
  __syncthreads();                      // LDS reuse
  uint2* pk = (uint2*)lds;              // [4 waves][64 rows]
  const float SC = 4194304.0f;          // 2^22

#pragma unroll
  for (int i = 0; i < 4; ++i) {
#pragma unroll
    for (int r = 0; r < 4; ++r) {
      unsigned k[4];
#pragma unroll
      for (int j = 0; j < 4; ++j) {
        const unsigned qv = (unsigned)((0.125f - acc[i][j][r]) * SC);
        k[j] = (qv << 7) | (unsigned)(wc * 64 + j * 16 + ml);
      }
      const unsigned m01 = min(k[0], k[1]), x01 = max(k[0], k[1]);
      const unsigned m23 = min(k[2], k[3]), x23 = max(k[2], k[3]);
      unsigned k1 = min(m01, m23);
      unsigned k2 = min(min(x01, x23), max(m01, m23));
      DPP_STAGE(0x121)   // row_ror:1
      DPP_STAGE(0x122)   // row_ror:2
      DPP_STAGE(0x124)   // row_ror:4
      DPP_STAGE(0x128)   // row_ror:8
      if (ml == 0) pk[w * 64 + (i * 16 + q * 4 + r)] = make_uint2(k1, k2);
    }
  }
  __syncthreads();
  if (t < 128) {
    const int wrh = t >> 6, lr = t & 63;
    const uint2 A2 = pk[(wrh * 2 + 0) * 64 + lr];
    const uint2 B2 = pk[(wrh * 2 + 1) * 64 + lr];
    const unsigned k1 = min(A2.x, B2.x);
    const unsigned k2 = min(min(A2.y, B2.y), max(A2.x, B2.x));
    const unsigned g1 = ((k1 >> 7) << 12) | ((unsigned)cb << 7) | (k1 & 127u);
    const unsigned g2 = ((k2 >> 7) << 12) | ((unsigned)cb << 7) | (k2 & 127u);
    const int row = rb * 128 + wrh * 64 + lr;
    partial[(size_t)row * 32 + cb] = make_uint2(g1, g2);
  }
}

// ---------------------------------------------------------------------------
// Exact np-semantics distance (byte-identical chain to rounds 2-11).
// ---------------------------------------------------------------------------
__device__ __forceinline__ float exact_d(const float* __restrict__ Z,
                                         const float* __restrict__ W,
                                         int row, int c, float a) {
  const float* z = Z + (size_t)row * DIMC;
  const float* w = W + (size_t)c * DIMC;
  float dot = 0.f;
  for (int d0 = 0; d0 < DIMC; d0 += 4) {
    const float4 zv = *(const float4*)(z + d0);
    const float4 wv = *(const float4*)(w + d0);
    dot = fmaf(zv.x, wv.x, dot);
    dot = fmaf(zv.y, wv.y, dot);
    dot = fmaf(zv.z, wv.z, dot);
    dot = fmaf(zv.w, wv.w, dot);
  }
  return a - 2.0f * dot;
}

// ---------------------------------------------------------------------------
// Fused tail: in-wave f64 row norm -> fp32 a; u32 merge of 32 key pairs;
// integer WIN gate; exact resolve for ambiguous rows; gather z_q, indices,
// per-block f64 loss partial + histogram. (merge/resolve validated r11)
// ---------------------------------------------------------------------------
__global__ __launch_bounds__(256)
void vq_tail(const float* __restrict__ Z, const float* __restrict__ W,
             const uint2* __restrict__ partial,
             float* __restrict__ zq_out, float* __restrict__ idx_out,
             double* __restrict__ lossp, int* __restrict__ hist) {
  __shared__ double sh[4];
  const int lane = threadIdx.x & 63, wv = threadIdx.x >> 6;
  const int row = blockIdx.x * 4 + wv;
  const float INF = 3.4e38f;

  const float4 z4 = *(const float4*)(Z + (size_t)row * DIMC + lane * 4);
  // row norm: f64 sum of squares -> fp32 (same value as the validated prep path)
  double ns = (double)z4.x * z4.x + (double)z4.y * z4.y +
              (double)z4.z * z4.z + (double)z4.w * z4.w;
#pragma unroll
  for (int mask = 1; mask < 64; mask <<= 1) ns += __shfl_xor(ns, mask);
  const float a = (float)ns;

  unsigned k1 = 0xFFFFFFFFu, k2 = 0xFFFFFFFFu;
  if (lane < 32) {
    const uint2 p = partial[(size_t)row * 32 + lane];
    k1 = p.x; k2 = p.y;
  }
  unsigned g1 = k1, g2 = k2;
#pragma unroll
  for (int mask = 1; mask < 32; mask <<= 1) {
    const unsigned og1 = (unsigned)__shfl_xor((int)g1, mask);
    const unsigned og2 = (unsigned)__shfl_xor((int)g2, mask);
    const unsigned mx = max(g1, og1);
    g1 = min(g1, og1);
    g2 = min(min(g2, og2), mx);
  }
  g1 = (unsigned)__shfl((int)g1, 0);
  g2 = (unsigned)__shfl((int)g2, 0);

  int k;
  const unsigned q1 = g1 >> 12;
  if ((g2 >> 12) - q1 > WINQ) {
    k = (int)(g1 & 4095u);
  } else {
    const bool scan   = (lane < 32) && ((k2 >> 12) <= q1 + WINQ);
    const bool single = (lane < 32) && !scan && ((k1 >> 12) <= q1 + WINQ);
    float bd = INF; int bi = 0x7fffffff;
    if (single) {
      const int c = (int)(k1 & 4095u);
      const float d = exact_d(Z, W, row, c, a);
      if (d < bd || (d == bd && c < bi)) { bd = d; bi = c; }
    }
    unsigned long long msk = __ballot(scan);
    while (msk) {
      const int cbk = __ffsll(msk) - 1; msk &= msk - 1;
#pragma unroll
      for (int h = 0; h < 2; ++h) {
        const int c = cbk * 128 + h * 64 + lane;
        const float d = exact_d(Z, W, row, c, a);
        if (d < bd || (d == bd && c < bi)) { bd = d; bi = c; }
      }
    }
#pragma unroll
    for (int mask = 1; mask < 64; mask <<= 1) {
      const float od = __shfl_xor(bd, mask);
      const int   oi = __shfl_xor(bi, mask);
      if (od < bd || (od == bd && oi < bi)) { bd = od; bi = oi; }
    }
    k = bi;
  }

  const float4 w4 = *(const float4*)(W + (size_t)k * DIMC + lane * 4);
  *(float4*)(zq_out + (size_t)row * DIMC + lane * 4) = w4;

  const double dx = (double)w4.x - (double)z4.x;
  const double dy = (double)w4.y - (double)z4.y;
  const double dz = (double)w4.z - (double)z4.z;
  const double dw = (double)w4.w - (double)z4.w;
  double l = dx * dx + dy * dy + dz * dz + dw * dw;
#pragma unroll
  for (int off = 32; off > 0; off >>= 1) l += __shfl_down(l, off);

  if (lane == 0) { sh[wv] = l; idx_out[row] = (float)k; atomicAdd(&hist[k], 1); }
  __syncthreads();
  if (threadIdx.x == 0) lossp[blockIdx.x] = sh[0] + sh[1] + sh[2] + sh[3];
}

// ---------------------------------------------------------------------------
// Final: sum per-block loss partials + entropy -> scalars.
// ---------------------------------------------------------------------------
__global__ __launch_bounds__(64)
void vq_final(const double* __restrict__ lossp, const int* __restrict__ hist,
              float* __restrict__ scal) {
  const int lane = threadIdx.x;
  double L = 0.0;
  for (int i = lane; i < NROWS / 4; i += 64) L += lossp[i];
  double H = 0.0;
  for (int k = lane; k < KC; k += 64) {
    const double p = (double)hist[k] / (double)NROWS;
    H -= p * log(p + 1e-10);
  }
#pragma unroll
  for (int off = 32; off > 0; off >>= 1) {
    L += __shfl_down(L, off);
    H += __shfl_down(H, off);
  }
  if (lane == 0) {
    scal[0] = (float)(L * 1.25 / ((double)NROWS * (double)DIMC));
    scal[1] = (float)exp(H);
  }
}

// ---------------------------------------------------------------------------
extern "C" void kernel_launch(void* const* d_in, const int* in_sizes, int n_in,
                              void* d_out, int out_size, void* d_ws, size_t ws_size,
                              hipStream_t stream) {
  const float* Z = (const float*)d_in[0];
  const float* W = (const float*)d_in[1];
  float* out = (float*)d_out;
  float* zq_out  = out;
  float* idx_out = out + (size_t)NROWS * DIMC;
  float* scal    = idx_out + NROWS;

  char* ws = (char*)d_ws;
  int*    hist       = (int*)(ws + 1024);                 // 16 KB
  double* lossp      = (double*)(ws + 524288);            // 64 KB (8192 f64)
  uint2*  partial    = (uint2*)(ws + 1048576);            // 8 MB @ 1 MB
  unsigned short* Zh = (unsigned short*)(ws + 20971520);  // 16 MB @ 20 MB
  unsigned short* Wh = (unsigned short*)(ws + 37748736);  // 2 MB  @ 36 MB

  hipMemsetAsync(ws, 0, 17408, stream);                   // hist
  vq_prep<<<1152, 256, 0, stream>>>(Z, W, Zh, Wh);
  vq_mfma<<<8192, 256, 0, stream>>>(Zh, Wh, partial);
  vq_tail<<<NROWS / 4, 256, 0, stream>>>(Z, W, partial, zq_out, idx_out, lossp, hist);
  vq_final<<<1, 64, 0, stream>>>(lossp, hist, scal);
}

// Round 13
// 229.434 us; speedup vs baseline: 2.2814x; 1.2742x over previous
//
#include <hip/hip_runtime.h>
#include <math.h>

constexpr int NROWS = 32768;   // B
constexpr int DIMC  = 256;     // D
constexpr int KC    = 4096;    // K

typedef __attribute__((ext_vector_type(8))) short short8;
typedef __attribute__((ext_vector_type(4))) float f32x4;

#define AS1 __attribute__((address_space(1)))
#define AS3 __attribute__((address_space(3)))

// ambiguity window: q units (1 q = 2^-21 in d). 420 q ~= 2.0e-4 (>=7 sigma of
// the bf16-h approx error difference, sigma ~2.8e-5 — flip risk ~1e-12/row).
#define WINQ 420u

__device__ __forceinline__ unsigned short f2bf(float x) {
  unsigned u = __float_as_uint(x);
  return (unsigned short)((u + 0x7fffu + ((u >> 16) & 1u)) >> 16);
}

// ---------------------------------------------------------------------------
// Pre-pass (convert-only): bf16 h-plane in the tiled swizzled layout
// (validated r3-r12). bid<1024 -> Z; else W.
// ---------------------------------------------------------------------------
__global__ __launch_bounds__(256)
void vq_prep(const float* __restrict__ Z, const float* __restrict__ W,
             unsigned short* __restrict__ Zh, unsigned short* __restrict__ Wh) {
  const bool isW = blockIdx.x >= 1024;
  const int bid  = isW ? ((int)blockIdx.x - 1024) : (int)blockIdx.x;
  const float* X = isW ? W : Z;
  unsigned short* out = isW ? Wh : Zh;
  const int blk = bid >> 2;
  const int kb0 = (bid & 3) * 2;
  const int t = threadIdx.x;

#pragma unroll
  for (int kk = 0; kk < 2; ++kk) {
    const int kb = kb0 + kk;
#pragma unroll
    for (int gi = 0; gi < 2; ++gi) {
      const int g = t + gi * 256;
      const int r = g >> 2, slot = g & 3;
      const int s8 = slot ^ ((r >> 1) & 3);
      const float* src = X + (size_t)(blk * 128 + r) * DIMC + kb * 32 + s8 * 8;
      short8 vh;
#pragma unroll
      for (int j = 0; j < 8; ++j) vh[j] = (short)f2bf(src[j]);
      *(short8*)(out + ((size_t)blk * 8 + kb) * 4096 + g * 8) = vh;
    }
  }
}

// ---------------------------------------------------------------------------
// Main GEMM (structure validated r12): A-direct from swizzled global, B via
// LDS (16 KB, BK=64, 8 barriers). NEW lean epilogue: fmaf keys + min-reduce
// DPP top-2 (global 2nd = min of {k1 of others} U {k2 of argmin lane}).
// ---------------------------------------------------------------------------
#define DPP_MIN4(v)                                                            \
  {                                                                            \
    unsigned _t;                                                               \
    _t = (unsigned)__builtin_amdgcn_update_dpp((int)(v), (int)(v), 0x121, 0xF, 0xF, false); \
    (v) = min((v), _t);                                                        \
    _t = (unsigned)__builtin_amdgcn_update_dpp((int)(v), (int)(v), 0x122, 0xF, 0xF, false); \
    (v) = min((v), _t);                                                        \
    _t = (unsigned)__builtin_amdgcn_update_dpp((int)(v), (int)(v), 0x124, 0xF, 0xF, false); \
    (v) = min((v), _t);                                                        \
    _t = (unsigned)__builtin_amdgcn_update_dpp((int)(v), (int)(v), 0x128, 0xF, 0xF, false); \
    (v) = min((v), _t);                                                        \
  }

__global__ __launch_bounds__(256, 4)
void vq_mfma(const unsigned short* __restrict__ Zh, const unsigned short* __restrict__ Wh,
             uint2* __restrict__ partial) {
  __shared__ char lds[16384];          // B: sec0 [0,8K), sec1 [8K,16K)
  const int t = threadIdx.x, lane = t & 63, w = t >> 6;
  const int rb = blockIdx.x >> 5, cb = blockIdx.x & 31;
  const int q = lane >> 4, ml = lane & 15;
  const int wr = w >> 1, wc = w & 1;

  const unsigned short* bsrc = Wh + (size_t)cb * 32768 + (w >> 1) * 4096
                             + (w & 1) * 2048 + lane * 8;
  char* bdst = lds + (w >> 1) * 8192 + (w & 1) * 4096;

  int aoff[4], boff[4];
#pragma unroll
  for (int i = 0; i < 4; ++i) {
    const int r = wr * 64 + i * 16 + ml;
    aoff[i] = (r * 4 + (q ^ ((r >> 1) & 3))) * 16;
    const int c = wc * 64 + i * 16 + ml;
    boff[i] = (c * 4 + (q ^ ((c >> 1) & 3))) * 16;
  }
  const char* Abase = (const char*)Zh + (size_t)rb * 65536;

  f32x4 acc[4][4];
#pragma unroll
  for (int i = 0; i < 4; ++i)
#pragma unroll
    for (int j = 0; j < 4; ++j) acc[i][j] = (f32x4){0.f, 0.f, 0.f, 0.f};

  for (int kb2 = 0; kb2 < 4; ++kb2) {
    __syncthreads();
#pragma unroll
    for (int i = 0; i < 4; ++i)
      __builtin_amdgcn_global_load_lds((const AS1 void*)(bsrc + kb2 * 8192 + i * 512),
                                       (AS3 void*)(bdst + i * 1024), 16, 0, 0);
    short8 Af[2][4];
#pragma unroll
    for (int sec = 0; sec < 2; ++sec) {
      const int kb = kb2 * 2 + sec;
#pragma unroll
      for (int i = 0; i < 4; ++i)
        Af[sec][i] = *(const short8*)(Abase + (size_t)kb * 8192 + aoff[i]);
    }
    __syncthreads();
#pragma unroll
    for (int sec = 0; sec < 2; ++sec) {
      short8 Bf[4];
#pragma unroll
      for (int i = 0; i < 4; ++i)
        Bf[i] = *(const short8*)(lds + sec * 8192 + boff[i]);
#pragma unroll
      for (int i = 0; i < 4; ++i)
#pragma unroll
        for (int j = 0; j < 4; ++j)
          acc[i][j] = __builtin_amdgcn_mfma_f32_16x16x32_bf16(Af[sec][i], Bf[j], acc[i][j], 0, 0, 0);
    }
  }

  // ------ lean u32-key epilogue ------
  __syncthreads();                      // LDS reuse
  uint2* pk = (uint2*)lds;              // [4 waves][64 rows]
  const float SCN = -4194304.0f;        // -(2^22): q = 524288 - acc*2^22

#pragma unroll
  for (int i = 0; i < 4; ++i) {
#pragma unroll
    for (int r = 0; r < 4; ++r) {
      unsigned k[4];
#pragma unroll
      for (int j = 0; j < 4; ++j) {
        const unsigned qv = (unsigned)fmaf(acc[i][j][r], SCN, 524288.0f);
        k[j] = (qv << 7) + (unsigned)(wc * 64 + j * 16 + ml);
      }
      const unsigned m01 = min(k[0], k[1]), x01 = max(k[0], k[1]);
      const unsigned m23 = min(k[2], k[3]), x23 = max(k[2], k[3]);
      const unsigned k1l = min(m01, m23);
      const unsigned k2l = min(max(m01, m23), min(x01, x23));
      unsigned m1 = k1l;
      DPP_MIN4(m1)
      unsigned c2 = (k1l == m1) ? k2l : k1l;
      DPP_MIN4(c2)
      if (ml == 0) pk[w * 64 + (i * 16 + q * 4 + r)] = make_uint2(m1, c2);
    }
  }
  __syncthreads();
  if (t < 128) {
    const int wrh = t >> 6, lr = t & 63;
    const uint2 A2 = pk[(wrh * 2 + 0) * 64 + lr];
    const uint2 B2 = pk[(wrh * 2 + 1) * 64 + lr];
    const unsigned k1 = min(A2.x, B2.x);
    const unsigned k2 = min(min(A2.y, B2.y), max(A2.x, B2.x));
    const unsigned g1 = ((k1 >> 7) << 12) | ((unsigned)cb << 7) | (k1 & 127u);
    const unsigned g2 = ((k2 >> 7) << 12) | ((unsigned)cb << 7) | (k2 & 127u);
    const int row = rb * 128 + wrh * 64 + lr;
    partial[(size_t)row * 32 + cb] = make_uint2(g1, g2);
  }
}

// ---------------------------------------------------------------------------
// Exact np-semantics distance (byte-identical chain to rounds 2-12).
// ---------------------------------------------------------------------------
__device__ __forceinline__ float exact_d(const float* __restrict__ Z,
                                         const float* __restrict__ W,
                                         int row, int c, float a) {
  const float* z = Z + (size_t)row * DIMC;
  const float* w = W + (size_t)c * DIMC;
  float dot = 0.f;
  for (int d0 = 0; d0 < DIMC; d0 += 4) {
    const float4 zv = *(const float4*)(z + d0);
    const float4 wv = *(const float4*)(w + d0);
    dot = fmaf(zv.x, wv.x, dot);
    dot = fmaf(zv.y, wv.y, dot);
    dot = fmaf(zv.z, wv.z, dot);
    dot = fmaf(zv.w, wv.w, dot);
  }
  return a - 2.0f * dot;
}

// ---------------------------------------------------------------------------
// Tail A: merge 32 key pairs per row, integer WIN gate; flagged rows compute
// the f64->fp32 norm in-wave and exact-resolve (validated r11/r12 rule).
// Writes the final index per row to kbuf. Touches Z only for flagged rows.
// ---------------------------------------------------------------------------
__global__ __launch_bounds__(256)
void vq_tailA(const float* __restrict__ Z, const float* __restrict__ W,
              const uint2* __restrict__ partial, int* __restrict__ kbuf) {
  const int lane = threadIdx.x & 63, wv = threadIdx.x >> 6;
  const int row = blockIdx.x * 4 + wv;
  const float INF = 3.4e38f;

  unsigned k1 = 0xFFFFFFFFu, k2 = 0xFFFFFFFFu;
  if (lane < 32) {
    const uint2 p = partial[(size_t)row * 32 + lane];
    k1 = p.x; k2 = p.y;
  }
  unsigned g1 = k1, g2 = k2;
#pragma unroll
  for (int mask = 1; mask < 32; mask <<= 1) {
    const unsigned og1 = (unsigned)__shfl_xor((int)g1, mask);
    const unsigned og2 = (unsigned)__shfl_xor((int)g2, mask);
    const unsigned mx = max(g1, og1);
    g1 = min(g1, og1);
    g2 = min(min(g2, og2), mx);
  }
  g1 = (unsigned)__shfl((int)g1, 0);
  g2 = (unsigned)__shfl((int)g2, 0);

  int k;
  const unsigned q1 = g1 >> 12;
  if ((g2 >> 12) - q1 > WINQ) {
    k = (int)(g1 & 4095u);
  } else {
    const float4 z4 = *(const float4*)(Z + (size_t)row * DIMC + lane * 4);
    double ns = (double)z4.x * z4.x + (double)z4.y * z4.y +
                (double)z4.z * z4.z + (double)z4.w * z4.w;
#pragma unroll
    for (int mask = 1; mask < 64; mask <<= 1) ns += __shfl_xor(ns, mask);
    const float a = (float)ns;

    const bool scan   = (lane < 32) && ((k2 >> 12) <= q1 + WINQ);
    const bool single = (lane < 32) && !scan && ((k1 >> 12) <= q1 + WINQ);
    float bd = INF; int bi = 0x7fffffff;
    if (single) {
      const int c = (int)(k1 & 4095u);
      const float d = exact_d(Z, W, row, c, a);
      if (d < bd || (d == bd && c < bi)) { bd = d; bi = c; }
    }
    unsigned long long msk = __ballot(scan);
    while (msk) {
      const int cbk = __ffsll(msk) - 1; msk &= msk - 1;
#pragma unroll
      for (int h = 0; h < 2; ++h) {
        const int c = cbk * 128 + h * 64 + lane;
        const float d = exact_d(Z, W, row, c, a);
        if (d < bd || (d == bd && c < bi)) { bd = d; bi = c; }
      }
    }
#pragma unroll
    for (int mask = 1; mask < 64; mask <<= 1) {
      const float od = __shfl_xor(bd, mask);
      const int   oi = __shfl_xor(bi, mask);
      if (od < bd || (od == bd && oi < bi)) { bd = od; bi = oi; }
    }
    k = bi;
  }
  if (lane == 0) kbuf[row] = k;
}

// ---------------------------------------------------------------------------
// Tail B: pure streaming — gather z_q, write indices, f64 loss per block,
// histogram. No divergence, no resolve stalls in the 32 MB write path.
// ---------------------------------------------------------------------------
__global__ __launch_bounds__(256)
void vq_tailB(const float* __restrict__ Z, const float* __restrict__ W,
              const int* __restrict__ kbuf, float* __restrict__ zq_out,
              float* __restrict__ idx_out, double* __restrict__ lossp,
              int* __restrict__ hist) {
  __shared__ double sh[4];
  const int lane = threadIdx.x & 63, wv = threadIdx.x >> 6;
  const int row = blockIdx.x * 4 + wv;

  const int k = kbuf[row];
  const float4 z4 = *(const float4*)(Z + (size_t)row * DIMC + lane * 4);
  const float4 w4 = *(const float4*)(W + (size_t)k   * DIMC + lane * 4);
  *(float4*)(zq_out + (size_t)row * DIMC + lane * 4) = w4;

  const double dx = (double)w4.x - (double)z4.x;
  const double dy = (double)w4.y - (double)z4.y;
  const double dz = (double)w4.z - (double)z4.z;
  const double dw = (double)w4.w - (double)z4.w;
  double l = dx * dx + dy * dy + dz * dz + dw * dw;
#pragma unroll
  for (int off = 32; off > 0; off >>= 1) l += __shfl_down(l, off);

  if (lane == 0) { sh[wv] = l; idx_out[row] = (float)k; atomicAdd(&hist[k], 1); }
  __syncthreads();
  if (threadIdx.x == 0) lossp[blockIdx.x] = sh[0] + sh[1] + sh[2] + sh[3];
}

// ---------------------------------------------------------------------------
// Final: 1024 threads — loss partial sum + entropy -> scalars.
// ---------------------------------------------------------------------------
__global__ __launch_bounds__(1024)
void vq_final(const double* __restrict__ lossp, const int* __restrict__ hist,
              float* __restrict__ scal) {
  __shared__ double sL[16], sH[16];
  const int t = threadIdx.x, lane = t & 63, wv = t >> 6;
  double L = 0.0, H = 0.0;
  for (int i = t; i < NROWS / 4; i += 1024) L += lossp[i];
  for (int k = t; k < KC; k += 1024) {
    const double p = (double)hist[k] / (double)NROWS;
    H -= p * log(p + 1e-10);
  }
#pragma unroll
  for (int off = 32; off > 0; off >>= 1) {
    L += __shfl_down(L, off);
    H += __shfl_down(H, off);
  }
  if (lane == 0) { sL[wv] = L; sH[wv] = H; }
  __syncthreads();
  if (t == 0) {
    double LT = 0.0, HT = 0.0;
#pragma unroll
    for (int i = 0; i < 16; ++i) { LT += sL[i]; HT += sH[i]; }
    scal[0] = (float)(LT * 1.25 / ((double)NROWS * (double)DIMC));
    scal[1] = (float)exp(HT);
  }
}

// ---------------------------------------------------------------------------
extern "C" void kernel_launch(void* const* d_in, const int* in_sizes, int n_in,
                              void* d_out, int out_size, void* d_ws, size_t ws_size,
                              hipStream_t stream) {
  const float* Z = (const float*)d_in[0];
  const float* W = (const float*)d_in[1];
  float* out = (float*)d_out;
  float* zq_out  = out;
  float* idx_out = out + (size_t)NROWS * DIMC;
  float* scal    = idx_out + NROWS;

  char* ws = (char*)d_ws;
  int*    hist       = (int*)(ws + 1024);                 // 16 KB
  int*    kbuf       = (int*)(ws + 262144);               // 128 KB
  double* lossp      = (double*)(ws + 524288);            // 64 KB
  uint2*  partial    = (uint2*)(ws + 1048576);            // 8 MB @ 1 MB
  unsigned short* Zh = (unsigned short*)(ws + 20971520);  // 16 MB @ 20 MB
  unsigned short* Wh = (unsigned short*)(ws + 37748736);  // 2 MB  @ 36 MB

  hipMemsetAsync(ws, 0, 17408, stream);                   // hist
  vq_prep<<<1152, 256, 0, stream>>>(Z, W, Zh, Wh);
  vq_mfma<<<8192, 256, 0, stream>>>(Zh, Wh, partial);
  vq_tailA<<<NROWS / 4, 256, 0, stream>>>(Z, W, partial, kbuf);
  vq_tailB<<<NROWS / 4, 256, 0, stream>>>(Z, W, kbuf, zq_out, idx_out, lossp, hist);
  vq_final<<<1, 1024, 0, stream>>>(lossp, hist, scal);
}